// Round 11
// baseline (265.973 us; speedup 1.0000x reference)
//
#include <hip/hip_runtime.h>
#include <stdint.h>

typedef short bf16x8 __attribute__((ext_vector_type(8)));
typedef short s16x4 __attribute__((ext_vector_type(4)));
typedef unsigned short us8 __attribute__((ext_vector_type(8)));
typedef float f32x4 __attribute__((ext_vector_type(4)));
typedef unsigned short u16;
typedef unsigned int u32;

__device__ __forceinline__ u16 f2bf(float f) {
    u32 u = __float_as_uint(f);
    return (u16)((u + 0x7FFFu + ((u >> 16) & 1u)) >> 16);   // RNE
}
__device__ __forceinline__ float bf2f(u16 h) { return __uint_as_float(((u32)h) << 16); }

typedef __attribute__((address_space(3))) unsigned int lds_uint;
typedef const __attribute__((address_space(1))) unsigned int glb_uint;
__device__ __forceinline__ void gld16(const void* g, void* l) {
    __builtin_amdgcn_global_load_lds((glb_uint*)g, (lds_uint*)l, 16, 0, 0);
}

#define VWAIT(n) asm volatile("s_waitcnt vmcnt(" #n ") lgkmcnt(0)" ::: "memory")
#define LWAIT    asm volatile("s_waitcnt lgkmcnt(0)" ::: "memory")
#define BARRIER  do { __builtin_amdgcn_s_barrier(); __builtin_amdgcn_sched_barrier(0); } while (0)

// ---- swizzled staging (rule #21: linear LDS dest + pre-swizzled per-lane global
//      source + matching XOR on the ds_read side) ----

// [128 rows][32 cols] bf16 tile; slot = g ^ ((row>>1)&3)
__device__ __forceinline__ void gld_p128x32(const u16* __restrict__ g, int64_t stride,
                                            u16* lds, int w, int lane) {
#pragma unroll
    for (int i = 0; i < 2; ++i) {
        const int grp = w * 2 + i;
        const int row = grp * 16 + (lane >> 2);
        const int sl = (lane & 3) ^ ((row >> 1) & 3);
        gld16(g + (int64_t)row * stride + (sl << 3), &lds[grp * 512]);
    }
}
__device__ __forceinline__ int idx128x32(int row, int gk) {
    return row * 32 + ((gk ^ ((row >> 1) & 3)) << 3);
}

// [R rows][128 cols] bf16 tile; slot = g ^ (row&7)
__device__ __forceinline__ void gld_t32x128(const u16* __restrict__ g, int64_t stride,
                                            u16* lds, int w, int lane) {
#pragma unroll
    for (int i = 0; i < 2; ++i) {
        const int gg = w * 2 + i;
        const int row = gg * 4 + (lane >> 4);
        const int gs = (lane & 15) ^ (row & 7);
        gld16(g + (int64_t)row * stride + (gs << 3), &lds[gg * 512]);
    }
}
__device__ __forceinline__ void gld_t64x128(const u16* __restrict__ g, int64_t stride,
                                            u16* lds, int w, int lane) {
#pragma unroll
    for (int i = 0; i < 4; ++i) {
        const int gg = w * 4 + i;
        const int row = gg * 4 + (lane >> 4);
        const int gs = (lane & 15) ^ (row & 7);
        gld16(g + (int64_t)row * stride + (gs << 3), &lds[gg * 512]);
    }
}
__device__ __forceinline__ int idxT(int row, int gk) {    // [*][128] read
    return row * 128 + ((gk ^ (row & 7)) << 3);
}

// [128 rows][64 cols] bf16 tile (V^T chunk); slot = g3 ^ (row&7)
__device__ __forceinline__ void gld_v128x64(const u16* __restrict__ g, int64_t stride,
                                            u16* lds, int w, int lane) {
#pragma unroll
    for (int i = 0; i < 4; ++i) {
        const int seg = w * 4 + i;
        const int row = seg * 8 + (lane >> 3);
        const int gs = (lane & 7) ^ (row & 7);
        gld16(g + (int64_t)row * stride + (gs << 3), &lds[seg * 512]);
    }
}
__device__ __forceinline__ int idxV(int row, int g3) {    // [128][64] read
    return row * 64 + ((g3 ^ (row & 7)) << 3);
}

// ---------------- K0: all four f32->bf16 conversions in one launch
__global__ void k0_all(const float* __restrict__ wqkv, const float* __restrict__ x,
                       const float* __restrict__ ctx, const float* __restrict__ wproj,
                       u16* __restrict__ Wh, u16* __restrict__ Xh,
                       u16* __restrict__ Phw) {
    const int gid = blockIdx.x;
    const float* src; u16* dst; int mode; int lg;
    if (gid < 1536)      { src = wqkv;  dst = Wh;  mode = 0; lg = gid; }
    else if (gid < 3584) { src = x;     dst = Xh;  mode = 1; lg = gid - 1536; }
    else if (gid < 5632) { src = ctx;   dst = Xh;  mode = 2; lg = gid - 3584; }
    else                 { src = wproj; dst = Phw; mode = 0; lg = gid - 5632; }
    const int64_t base = ((int64_t)lg * 256 + threadIdx.x) * 8;
    const int row = (int)(base >> 10), col = (int)(base & 1023);
    int orow = row;
    if (mode == 1) orow = row + ((row >> 10) << 10);
    else if (mode == 2) orow = row + (((row >> 10) + 1) << 10);
    const float4* sp = reinterpret_cast<const float4*>(src + base);
    float4 a = sp[0], b = sp[1];
    float v[8] = {a.x, a.y, a.z, a.w, b.x, b.y, b.z, b.w};
    us8 hh;
#pragma unroll
    for (int j = 0; j < 8; ++j) hh[j] = f2bf(v[j]);
    *reinterpret_cast<us8*>(&dst[(int64_t)orow * 1024 + col]) = hh;
}

// ---- 256x128-tile 8-wave GEMM core staging (512 threads) ----
// A tile [256 rows][32 k] (16 KB, 2 gld16/thread), B tile [128 rows][32 k] (8 KB, 1)
#define STAGE_A(Ab, t, buf) do {                                               \
    const int r0_ = (tid >> 2), s0_ = (tid & 3) ^ ((r0_ >> 1) & 3);            \
    gld16((Ab) + (int64_t)r0_ * 1024 + (t) * 32 + (s0_ << 3),                  \
          &LA[buf][tid * 8]);                                                  \
    const int r1_ = 128 + (tid >> 2), s1_ = (tid & 3) ^ ((r1_ >> 1) & 3);      \
    gld16((Ab) + (int64_t)r1_ * 1024 + (t) * 32 + (s1_ << 3),                  \
          &LA[buf][4096 + tid * 8]); } while (0)
#define STAGE_B(Bb, t, buf) do {                                               \
    const int rb_ = (tid >> 2), sb_ = (tid & 3) ^ ((rb_ >> 1) & 3);            \
    gld16((Bb) + (int64_t)rb_ * 1024 + (t) * 32 + (sb_ << 3),                  \
          &LB[buf][tid * 8]); } while (0)

// ---------------- K1: qkv = xc @ w_qkv^T -> Qh (bf16)
// 256x128 tile, 8 waves, BK=32, 3-buffer 2-ahead counted-vmcnt, setprio MFMA.
__global__ __launch_bounds__(512) void k1_qkv(const u16* __restrict__ Xh,
                                              const u16* __restrict__ Wh,
                                              u16* __restrict__ Qh) {
    __shared__ u16 LA[3][8192], LB[3][4096];
    const int tid = threadIdx.x, lane = tid & 63;
    const int w = tid >> 6, wm = w >> 2, wn = w & 3;
    const int n0 = blockIdx.x << 7, m0 = blockIdx.y << 8;
    const u16* Ab = Xh + (int64_t)m0 * 1024;
    const u16* Bb = Wh + (int64_t)n0 * 1024;
    const int rl = lane & 15, gk = lane >> 4;
    f32x4 acc[8][2] = {};
    STAGE_A(Ab, 0, 0); STAGE_B(Bb, 0, 0);
    STAGE_A(Ab, 1, 1); STAGE_B(Bb, 1, 1);
    for (int t = 0; t < 32; ++t) {
        if (t == 31) { VWAIT(0); } else { VWAIT(3); }   // chunk t landed; t+1 in flight
        BARRIER;
        if (t < 30) {
            const int nb = (t + 2) % 3;
            STAGE_A(Ab, t + 2, nb);
            STAGE_B(Bb, t + 2, nb);
        }
        const u16* A = LA[t % 3];
        const u16* B = LB[t % 3];
        bf16x8 bfr0 = *reinterpret_cast<const bf16x8*>(&B[idx128x32(wn * 32 + rl, gk)]);
        bf16x8 bfr1 = *reinterpret_cast<const bf16x8*>(&B[idx128x32(wn * 32 + 16 + rl, gk)]);
        __builtin_amdgcn_s_setprio(1);
#pragma unroll
        for (int m = 0; m < 8; ++m) {
            bf16x8 a = *reinterpret_cast<const bf16x8*>(&A[idx128x32(wm * 128 + m * 16 + rl, gk)]);
            acc[m][0] = __builtin_amdgcn_mfma_f32_16x16x32_bf16(a, bfr0, acc[m][0], 0, 0, 0);
            acc[m][1] = __builtin_amdgcn_mfma_f32_16x16x32_bf16(a, bfr1, acc[m][1], 0, 0, 0);
        }
        __builtin_amdgcn_s_setprio(0);
    }
    const int r4 = gk << 2, cc = rl;
#pragma unroll
    for (int m = 0; m < 8; ++m)
#pragma unroll
        for (int n = 0; n < 2; ++n)
#pragma unroll
            for (int j = 0; j < 4; ++j)
                Qh[(int64_t)(m0 + wm * 128 + m * 16 + r4 + j) * 3072
                   + (n0 + wn * 32 + n * 16 + cc)] = f2bf(acc[m][n][j]);
}

// ---------------- K0v: pre-transpose V planes: Vt[z][e 128][kpos 1024]
__global__ __launch_bounds__(256, 2) void k0v_vt(const u16* __restrict__ Qh,
                                                 u16* __restrict__ Vt) {
    __shared__ u16 T[128][144];
    const int tid = threadIdx.x;
    const int z = blockIdx.y, b = z >> 4, h = z & 15;
    const int kt = blockIdx.x;                       // 128-kpos tile
    const int c0v = (h < 8) ? (1024 + h * 128) : (2048 + (h - 8) * 128);
    const u16* Vbase = Qh + ((int64_t)b * 2048 + 1) * 3072 + c0v;
    const int row = tid >> 1, e0 = (tid & 1) << 6;
    const u16* src = Vbase + (int64_t)(kt * 128 + row) * 6144 + e0;
#pragma unroll
    for (int i = 0; i < 8; ++i) {
        us8 v = *reinterpret_cast<const us8*>(src + i * 8);
#pragma unroll
        for (int j = 0; j < 8; ++j) T[e0 + i * 8 + j][row] = v[j];
    }
    __syncthreads();
    const int e = tid >> 1, k0 = (tid & 1) << 6;
    u16* dst = Vt + ((int64_t)z << 17) + (int64_t)e * 1024 + kt * 128 + k0;
#pragma unroll
    for (int i = 0; i < 8; ++i)
        *reinterpret_cast<us8*>(dst + i * 8) = *reinterpret_cast<const us8*>(&T[e][k0 + i * 8]);
}

// ---------------- K23 v3 (frozen from R10): fused attention, swapped QK^T,
// S^T in regs, direct float4 attn stores, M=0 softmax.
__global__ __launch_bounds__(256, 2) void k23_fused(const u16* __restrict__ Qh,
                                                    const u16* __restrict__ Vt,
                                                    float* __restrict__ attn,
                                                    u16* __restrict__ Obf) {
    __shared__ u16 LQ[4096];                         // 32x128
    __shared__ u16 LKV[3][8192];                     // 3 x (64x128 K | 128x64 V^T)
    __shared__ u16 Ph[32 * 72];                      // p~ bf16 [q][k] (+pad)
    __shared__ float pS[4][32];
    __shared__ float rowInv[32];
    const int tid = threadIdx.x, lane = tid & 63, w = tid >> 6;
    const u32 wgid = blockIdx.x;
    const int xcd = wgid & 7, t0 = wgid >> 3;        // T1: same-z -> same XCD
    const int mt = t0 & 31, z = ((t0 >> 5) << 3) + xcd;
    const int b = z >> 4, h = z & 15;
    const int m0 = mt << 5;                          // 32 q-rows per block
    const u16* Qbase = Qh + ((int64_t)b * 2048 + 2 * m0) * 3072 + h * 128;
    const int pk  = (h < 8) ? 0 : 1;
    const int c0k = (h < 8) ? (2048 + h * 128) : ((h - 8) * 128);
    const u16* Kbase = Qh + ((int64_t)b * 2048 + pk) * 3072 + c0k;
    const u16* Vtz = Vt + ((int64_t)z << 17);
    float* attnZ = attn + ((int64_t)z << 20) + (int64_t)m0 * 1024;
    const int rl = lane & 15, gk = lane >> 4;
    const int r4 = gk << 2;
    const int sm = w & 1, sn = w >> 1;               // PV roles: q-half, e-half
    gld_t32x128(Qbase, 6144, LQ, w, lane);
    gld_t64x128(Kbase,             6144, LKV[0], w, lane);
    gld_t64x128(Kbase + 64 * 6144, 6144, LKV[1], w, lane);
    // ---- pass 1: S^T into regs (mfma(K,Q): D[row=k_sub][col=q])
    f32x4 sfr[32];
#pragma unroll
    for (int t = 0; t < 16; ++t) {
        if (t == 15) { VWAIT(0); } else { VWAIT(4); }
        BARRIER;
        if (t < 14)
            gld_t64x128(Kbase + (int64_t)(t + 2) * 64 * 6144, 6144, LKV[(t + 2) % 3], w, lane);
        f32x4 s0 = {}, s1 = {};
#pragma unroll
        for (int ks = 0; ks < 4; ++ks) {
            bf16x8 kf = *reinterpret_cast<const bf16x8*>(&LKV[t % 3][idxT(w * 16 + rl, ks * 4 + gk)]);
            bf16x8 q0 = *reinterpret_cast<const bf16x8*>(&LQ[idxT(rl, ks * 4 + gk)]);
            bf16x8 q1 = *reinterpret_cast<const bf16x8*>(&LQ[idxT(16 + rl, ks * 4 + gk)]);
            s0 = __builtin_amdgcn_mfma_f32_16x16x32_bf16(kf, q0, s0, 0, 0, 0);
            s1 = __builtin_amdgcn_mfma_f32_16x16x32_bf16(kf, q1, s1, 0, 0, 0);
        }
        sfr[2 * t] = s0;
        sfr[2 * t + 1] = s1;
    }
    // ---- stats (register-only): sumexp per q, reduce over k
    float ssum0 = 0.f, ssum1 = 0.f;
#pragma unroll
    for (int t = 0; t < 16; ++t)
#pragma unroll
        for (int j = 0; j < 4; ++j) {
            ssum0 += __expf(sfr[2 * t][j] * 0.125f);
            ssum1 += __expf(sfr[2 * t + 1][j] * 0.125f);
        }
    ssum0 += __shfl_xor(ssum0, 16); ssum0 += __shfl_xor(ssum0, 32);
    ssum1 += __shfl_xor(ssum1, 16); ssum1 += __shfl_xor(ssum1, 32);
    if (lane < 16) { pS[w][lane] = ssum0; pS[w][16 + lane] = ssum1; }
    LWAIT; BARRIER;
    gld_v128x64(Vtz,      1024, LKV[0], w, lane);
    gld_v128x64(Vtz + 64, 1024, LKV[1], w, lane);
    if (tid < 32)
        rowInv[tid] = 1.0f / (pS[0][tid] + pS[1][tid] + pS[2][tid] + pS[3][tid]);
    LWAIT; BARRIER;
    const float Iq0 = rowInv[rl], Iq1 = rowInv[16 + rl];
    float IqO[4];
#pragma unroll
    for (int j = 0; j < 4; ++j) IqO[j] = rowInv[sm * 16 + r4 + j];
    // ---- pass 2: p~ -> Ph + direct attn stores + PV
    f32x4 po[4] = {};
#pragma unroll
    for (int t = 0; t < 16; ++t) {
        if (t == 0)       { VWAIT(4); }
        else if (t == 15) { VWAIT(2); }
        else              { VWAIT(6); }
        BARRIER;
        if (t < 14)
            gld_v128x64(Vtz + (t + 2) * 64, 1024, LKV[(t + 2) % 3], w, lane);
        f32x4 s0 = sfr[2 * t], s1 = sfr[2 * t + 1];
        float p0[4], p1[4];
        s16x4 h0, h1;
#pragma unroll
        for (int j = 0; j < 4; ++j) {
            p0[j] = __expf(s0[j] * 0.125f);
            p1[j] = __expf(s1[j] * 0.125f);
            h0[j] = (short)f2bf(p0[j]);
            h1[j] = (short)f2bf(p1[j]);
        }
        *reinterpret_cast<s16x4*>(&Ph[rl * 72 + w * 16 + r4])        = h0;
        *reinterpret_cast<s16x4*>(&Ph[(16 + rl) * 72 + w * 16 + r4]) = h1;
        *reinterpret_cast<float4*>(&attnZ[(int64_t)rl * 1024 + t * 64 + w * 16 + r4])
            = make_float4(p0[0] * Iq0, p0[1] * Iq0, p0[2] * Iq0, p0[3] * Iq0);
        *reinterpret_cast<float4*>(&attnZ[(int64_t)(16 + rl) * 1024 + t * 64 + w * 16 + r4])
            = make_float4(p1[0] * Iq1, p1[1] * Iq1, p1[2] * Iq1, p1[3] * Iq1);
        LWAIT; BARRIER;                              // Ph visible (stores NOT drained)
        bf16x8 pa0 = *reinterpret_cast<const bf16x8*>(&Ph[(sm * 16 + rl) * 72 + gk * 8]);
        bf16x8 pa1 = *reinterpret_cast<const bf16x8*>(&Ph[(sm * 16 + rl) * 72 + 32 + gk * 8]);
#pragma unroll
        for (int n = 0; n < 4; ++n) {
            bf16x8 bv0 = *reinterpret_cast<const bf16x8*>(&LKV[t % 3][idxV(sn * 64 + n * 16 + rl, gk)]);
            bf16x8 bv1 = *reinterpret_cast<const bf16x8*>(&LKV[t % 3][idxV(sn * 64 + n * 16 + rl, 4 + gk)]);
            po[n] = __builtin_amdgcn_mfma_f32_16x16x32_bf16(pa0, bv0, po[n], 0, 0, 0);
            po[n] = __builtin_amdgcn_mfma_f32_16x16x32_bf16(pa1, bv1, po[n], 0, 0, 0);
        }
    }
    const int poh = h >> 3, cb2 = (h & 7) << 7;
#pragma unroll
    for (int n = 0; n < 4; ++n)
#pragma unroll
        for (int j = 0; j < 4; ++j) {
            const int qrow = m0 + sm * 16 + r4 + j;
            Obf[((int64_t)b * 2048 + 2 * qrow + poh) * 1024
                + cb2 + sn * 64 + n * 16 + rl] = f2bf(po[n][j] * IqO[j]);
        }
}

// ---------------- K4: out = o @ w_proj^T + b_proj (f32 out)
// same 256x128-tile 8-wave counted-vmcnt structure as k1.
__global__ __launch_bounds__(512) void k4_out(const u16* __restrict__ Obf,
                                              const u16* __restrict__ Phw,
                                              const float* __restrict__ bias,
                                              float* __restrict__ out) {
    __shared__ u16 LA[3][8192], LB[3][4096];
    const int tid = threadIdx.x, lane = tid & 63;
    const int w = tid >> 6, wm = w >> 2, wn = w & 3;
    const int n0 = blockIdx.x << 7, m0 = blockIdx.y << 8;
    const u16* Ab = Obf + (int64_t)m0 * 1024;
    const u16* Bb = Phw + (int64_t)n0 * 1024;
    const int rl = lane & 15, gk = lane >> 4;
    f32x4 acc[8][2] = {};
    STAGE_A(Ab, 0, 0); STAGE_B(Bb, 0, 0);
    STAGE_A(Ab, 1, 1); STAGE_B(Bb, 1, 1);
    for (int t = 0; t < 32; ++t) {
        if (t == 31) { VWAIT(0); } else { VWAIT(3); }
        BARRIER;
        if (t < 30) {
            const int nb = (t + 2) % 3;
            STAGE_A(Ab, t + 2, nb);
            STAGE_B(Bb, t + 2, nb);
        }
        const u16* A = LA[t % 3];
        const u16* B = LB[t % 3];
        bf16x8 bfr0 = *reinterpret_cast<const bf16x8*>(&B[idx128x32(wn * 32 + rl, gk)]);
        bf16x8 bfr1 = *reinterpret_cast<const bf16x8*>(&B[idx128x32(wn * 32 + 16 + rl, gk)]);
        __builtin_amdgcn_s_setprio(1);
#pragma unroll
        for (int m = 0; m < 8; ++m) {
            bf16x8 a = *reinterpret_cast<const bf16x8*>(&A[idx128x32(wm * 128 + m * 16 + rl, gk)]);
            acc[m][0] = __builtin_amdgcn_mfma_f32_16x16x32_bf16(a, bfr0, acc[m][0], 0, 0, 0);
            acc[m][1] = __builtin_amdgcn_mfma_f32_16x16x32_bf16(a, bfr1, acc[m][1], 0, 0, 0);
        }
        __builtin_amdgcn_s_setprio(0);
    }
    const int r4 = gk << 2, cc = rl;
#pragma unroll
    for (int m = 0; m < 8; ++m)
#pragma unroll
        for (int n = 0; n < 2; ++n) {
            const float bb = bias[n0 + wn * 32 + n * 16 + cc];
#pragma unroll
            for (int j = 0; j < 4; ++j)
                out[(int64_t)(m0 + wm * 128 + m * 16 + r4 + j) * 1024
                    + (n0 + wn * 32 + n * 16 + cc)] = acc[m][n][j] + bb;
        }
}

extern "C" void kernel_launch(void* const* d_in, const int* in_sizes, int n_in,
                              void* d_out, int out_size, void* d_ws, size_t ws_size,
                              hipStream_t stream) {
    const float* x     = (const float*)d_in[0];
    const float* ctx   = (const float*)d_in[1];
    const float* wqkv  = (const float*)d_in[2];
    const float* wproj = (const float*)d_in[3];
    const float* bias  = (const float*)d_in[4];
    float* out  = (float*)d_out;                 // [4,2048,1024]
    float* attn = out + 8388608;                 // [4,16,1024,1024] f32

    // ws (u16), total 92.3 MB
    u16* Qh  = (u16*)d_ws;                       // [8192,3072]
    u16* Vt  = Qh + 25165824;                    // [64,128,1024]
    u16* Wh  = Vt + 8388608;                     // [3072,1024]
    u16* Phw = Wh + 3145728;                     // [1024,1024]
    u16* Obf = Phw + 1048576;                    // [8192,1024]

    // X bf16 plane parked in the attn region (dead once k1 finishes)
    u16* Xh = (u16*)attn;                        // [8192,1024]

    k0_all   <<<dim3(6144),   256, 0, stream>>>(wqkv, x, ctx, wproj, Wh, Xh, Phw);
    k1_qkv   <<<dim3(24, 32), 512, 0, stream>>>(Xh, Wh, Qh);
    k0v_vt   <<<dim3(8, 64),  256, 0, stream>>>(Qh, Vt);
    k23_fused<<<dim3(2048),   256, 0, stream>>>(Qh, Vt, attn, Obf);
    k4_out   <<<dim3(8, 32),  512, 0, stream>>>(Obf, Phw, bias, out);
}

// Round 12
// 253.931 us; speedup vs baseline: 1.0474x; 1.0474x over previous
//
#include <hip/hip_runtime.h>
#include <stdint.h>

typedef short bf16x8 __attribute__((ext_vector_type(8)));
typedef short s16x4 __attribute__((ext_vector_type(4)));
typedef unsigned short us8 __attribute__((ext_vector_type(8)));
typedef float f32x4 __attribute__((ext_vector_type(4)));
typedef unsigned short u16;
typedef unsigned int u32;

__device__ __forceinline__ u16 f2bf(float f) {
    u32 u = __float_as_uint(f);
    return (u16)((u + 0x7FFFu + ((u >> 16) & 1u)) >> 16);   // RNE
}
__device__ __forceinline__ float bf2f(u16 h) { return __uint_as_float(((u32)h) << 16); }

__device__ __forceinline__ u32 cvtpk(float lo, float hi) {   // 2xbf16 RNE pack
    u32 r;
    asm("v_cvt_pk_bf16_f32 %0, %1, %2" : "=v"(r) : "v"(lo), "v"(hi));
    return r;
}

typedef __attribute__((address_space(3))) unsigned int lds_uint;
typedef const __attribute__((address_space(1))) unsigned int glb_uint;
__device__ __forceinline__ void gld16(const void* g, void* l) {
    __builtin_amdgcn_global_load_lds((glb_uint*)g, (lds_uint*)l, 16, 0, 0);
}

#define VWAIT(n) asm volatile("s_waitcnt vmcnt(" #n ") lgkmcnt(0)" ::: "memory")
#define LWAIT    asm volatile("s_waitcnt lgkmcnt(0)" ::: "memory")
#define BARRIER  do { __builtin_amdgcn_s_barrier(); __builtin_amdgcn_sched_barrier(0); } while (0)

// ---- swizzled staging (rule #21: linear LDS dest + pre-swizzled per-lane global
//      source + matching XOR on the ds_read side) ----

// [128 rows][32 cols] bf16 tile (4-wave); slot = g ^ ((row>>1)&3)
__device__ __forceinline__ void gld_p128x32(const u16* __restrict__ g, int64_t stride,
                                            u16* lds, int w, int lane) {
#pragma unroll
    for (int i = 0; i < 2; ++i) {
        const int grp = w * 2 + i;
        const int row = grp * 16 + (lane >> 2);
        const int sl = (lane & 3) ^ ((row >> 1) & 3);
        gld16(g + (int64_t)row * stride + (sl << 3), &lds[grp * 512]);
    }
}
__device__ __forceinline__ int idx128x32(int row, int gk) {
    return row * 32 + ((gk ^ ((row >> 1) & 3)) << 3);
}

// [64 rows][128 cols] bf16 tile, 8-wave staging; slot = g ^ (row&7)
__device__ __forceinline__ void gld8_t64x128(const u16* __restrict__ g, int64_t stride,
                                             u16* lds, int w, int lane) {
#pragma unroll
    for (int i = 0; i < 2; ++i) {
        const int gg = w * 2 + i;                     // 0..15 -> rows gg*4..+3
        const int row = gg * 4 + (lane >> 4);
        const int gs = (lane & 15) ^ (row & 7);
        gld16(g + (int64_t)row * stride + (gs << 3), &lds[gg * 512]);
    }
}
__device__ __forceinline__ int idxT(int row, int gk) {    // [*][128] read
    return row * 128 + ((gk ^ (row & 7)) << 3);
}

// [128 rows][64 cols] bf16 tile (V^T chunk), 8-wave staging; slot = g3 ^ (row&7)
__device__ __forceinline__ void gld8_v128x64(const u16* __restrict__ g, int64_t stride,
                                             u16* lds, int w, int lane) {
#pragma unroll
    for (int i = 0; i < 2; ++i) {
        const int seg = w * 2 + i;                    // 0..15 -> rows seg*8..+7
        const int row = seg * 8 + (lane >> 3);
        const int gs = (lane & 7) ^ (row & 7);
        gld16(g + (int64_t)row * stride + (gs << 3), &lds[seg * 512]);
    }
}

// hi-only MFMA step on two swizzled [128][32] planes (4 waves, 64x64 per wave)
__device__ __forceinline__ void mfma_step1(const u16* LA, const u16* LB,
                                           int wrow, int wcol, int lane,
                                           f32x4 acc[4][4]) {
    const int rl = lane & 15, gk = lane >> 4;
    bf16x8 a[4], bv[4];
#pragma unroll
    for (int i = 0; i < 4; ++i) {
        a[i]  = *reinterpret_cast<const bf16x8*>(&LA[idx128x32(wrow + i * 16 + rl, gk)]);
        bv[i] = *reinterpret_cast<const bf16x8*>(&LB[idx128x32(wcol + i * 16 + rl, gk)]);
    }
#pragma unroll
    for (int m = 0; m < 4; ++m)
#pragma unroll
        for (int n = 0; n < 4; ++n)
            acc[m][n] = __builtin_amdgcn_mfma_f32_16x16x32_bf16(a[m], bv[n], acc[m][n], 0, 0, 0);
}

// ---------------- K0: all four f32->bf16 conversions in one launch
__global__ void k0_all(const float* __restrict__ wqkv, const float* __restrict__ x,
                       const float* __restrict__ ctx, const float* __restrict__ wproj,
                       u16* __restrict__ Wh, u16* __restrict__ Xh,
                       u16* __restrict__ Phw) {
    const int gid = blockIdx.x;
    const float* src; u16* dst; int mode; int lg;
    if (gid < 1536)      { src = wqkv;  dst = Wh;  mode = 0; lg = gid; }
    else if (gid < 3584) { src = x;     dst = Xh;  mode = 1; lg = gid - 1536; }
    else if (gid < 5632) { src = ctx;   dst = Xh;  mode = 2; lg = gid - 3584; }
    else                 { src = wproj; dst = Phw; mode = 0; lg = gid - 5632; }
    const int64_t base = ((int64_t)lg * 256 + threadIdx.x) * 8;
    const int row = (int)(base >> 10), col = (int)(base & 1023);
    int orow = row;
    if (mode == 1) orow = row + ((row >> 10) << 10);
    else if (mode == 2) orow = row + (((row >> 10) + 1) << 10);
    const float4* sp = reinterpret_cast<const float4*>(src + base);
    float4 a = sp[0], b = sp[1];
    float v[8] = {a.x, a.y, a.z, a.w, b.x, b.y, b.z, b.w};
    us8 hh;
#pragma unroll
    for (int j = 0; j < 8; ++j) hh[j] = f2bf(v[j]);
    *reinterpret_cast<us8*>(&dst[(int64_t)orow * 1024 + col]) = hh;
}

// ---------------- K1: qkv = xc @ w_qkv^T  (hi-only bf16) -> Qh  [R8 proven form]
__global__ __launch_bounds__(256, 2) void k1_qkv(const u16* __restrict__ Xh,
                                                 const u16* __restrict__ Wh,
                                                 u16* __restrict__ Qh) {
    __shared__ u16 LA[4096], LB[4096];
    const int tid = threadIdx.x, lane = tid & 63, w = tid >> 6;
    const int wrow = (w >> 1) << 6, wcol = (w & 1) << 6;
    const int n0 = blockIdx.x << 7, m0 = blockIdx.y << 7;
    const u16* Ab = Xh + (int64_t)m0 * 1024;
    const u16* Bb = Wh + (int64_t)n0 * 1024;
    f32x4 acc[4][4] = {};
    for (int kb = 0; kb < 32; ++kb) {
        gld_p128x32(Ab + kb * 32, 1024, LA, w, lane);
        gld_p128x32(Bb + kb * 32, 1024, LB, w, lane);
        __syncthreads();
        mfma_step1(LA, LB, wrow, wcol, lane, acc);
        __syncthreads();
    }
    const int r4 = (lane >> 4) << 2, cc = lane & 15;
#pragma unroll
    for (int m = 0; m < 4; ++m)
#pragma unroll
        for (int n = 0; n < 4; ++n)
#pragma unroll
            for (int j = 0; j < 4; ++j)
                Qh[(int64_t)(m0 + wrow + m * 16 + r4 + j) * 3072
                   + (n0 + wcol + n * 16 + cc)] = f2bf(acc[m][n][j]);
}

// ---------------- K0v: pre-transpose V planes: Vt[z][e 128][kpos 1024]
__global__ __launch_bounds__(256, 2) void k0v_vt(const u16* __restrict__ Qh,
                                                 u16* __restrict__ Vt) {
    __shared__ u16 T[128][144];
    const int tid = threadIdx.x;
    const int z = blockIdx.y, b = z >> 4, h = z & 15;
    const int kt = blockIdx.x;                       // 128-kpos tile
    const int c0v = (h < 8) ? (1024 + h * 128) : (2048 + (h - 8) * 128);
    const u16* Vbase = Qh + ((int64_t)b * 2048 + 1) * 3072 + c0v;
    const int row = tid >> 1, e0 = (tid & 1) << 6;
    const u16* src = Vbase + (int64_t)(kt * 128 + row) * 6144 + e0;
#pragma unroll
    for (int i = 0; i < 8; ++i) {
        us8 v = *reinterpret_cast<const us8*>(src + i * 8);
#pragma unroll
        for (int j = 0; j < 8; ++j) T[e0 + i * 8 + j][row] = v[j];
    }
    __syncthreads();
    const int e = tid >> 1, k0 = (tid & 1) << 6;
    u16* dst = Vt + ((int64_t)z << 17) + (int64_t)e * 1024 + kt * 128 + k0;
#pragma unroll
    for (int i = 0; i < 8; ++i)
        *reinterpret_cast<us8*>(dst + i * 8) = *reinterpret_cast<const us8*>(&T[e][k0 + i * 8]);
}

// ---------------- K23 v4: QBLK=64, 8 waves = (qs 0..3) x (kh 0..1).
// Pass 1: swapped mfma(K,Q) -> lane holds q=lane&15 (A-row mapping for PV!),
//         k spread over OWN wave only (kh-half, gk*4+j slots).
// Pass 2: P lane-local -> cvt_pk bf16 A-frag from own regs; k-slot permutation
//         absorbed into V-side ds_read_b64 pairs. NO P LDS, ONE barrier/chunk.
// End: cross-kh O-partial reduce via LDS; reg-direct attn f32 stores throughout.
__global__ __launch_bounds__(512, 2) void k23_fused(const u16* __restrict__ Qh,
                                                    const u16* __restrict__ Vt,
                                                    float* __restrict__ attn,
                                                    u16* __restrict__ Obf) {
    __shared__ u16 LQ[8192];                         // 64x128
    __shared__ u16 LKV[3][8192];                     // 3 x (64x128 K | 128x64 V^T)
    __shared__ float pS[8][16];
    __shared__ float rowInv[64];
    const int tid = threadIdx.x, lane = tid & 63, w = tid >> 6;
    const u32 wgid = blockIdx.x;
    const int xcd = wgid & 7, t0 = wgid >> 3;        // T1: same-z -> same XCD
    const int qt = t0 & 15, z = ((t0 >> 4) << 3) + xcd;
    const int b = z >> 4, h = z & 15;
    const int m0 = qt << 6;                          // 64 q-rows per block
    const int qs = w & 3, kh = w >> 2;               // wave role
    const int rl = lane & 15, gk = lane >> 4;
    const u16* Qbase = Qh + ((int64_t)b * 2048 + 2 * m0) * 3072 + h * 128;
    const int pk  = (h < 8) ? 0 : 1;
    const int c0k = (h < 8) ? (2048 + h * 128) : ((h - 8) * 128);
    const u16* Kbase = Qh + ((int64_t)b * 2048 + pk) * 3072 + c0k;
    const u16* Vtz = Vt + ((int64_t)z << 17);
    float* attnZ = attn + ((int64_t)z << 20) + (int64_t)m0 * 1024;
    // prologue: Q (64x128) + K chunks 0,1 (2 staging instrs each per thread)
    gld8_t64x128(Qbase, 6144, LQ, w, lane);
    gld8_t64x128(Kbase,             6144, LKV[0], w, lane);
    gld8_t64x128(Kbase + 64 * 6144, 6144, LKV[1], w, lane);
    // ---- pass 1: S^T subtiles into regs.
    // sfr[2t+T][j] = S[q = m0+qs*16+rl][k = t*64 + kh*32 + T*16 + gk*4 + j]
    f32x4 sfr[32];
#pragma unroll
    for (int t = 0; t < 16; ++t) {
        if (t == 15) { VWAIT(0); } else { VWAIT(2); }   // K(t) landed; K(t+1) in flight
        BARRIER;
        if (t < 14)
            gld8_t64x128(Kbase + (int64_t)(t + 2) * 64 * 6144, 6144, LKV[(t + 2) % 3], w, lane);
#pragma unroll
        for (int T = 0; T < 2; ++T) {
            f32x4 s = {};
#pragma unroll
            for (int ks = 0; ks < 4; ++ks) {
                bf16x8 kf = *reinterpret_cast<const bf16x8*>(
                    &LKV[t % 3][idxT(kh * 32 + T * 16 + rl, ks * 4 + gk)]);
                bf16x8 qf = *reinterpret_cast<const bf16x8*>(
                    &LQ[idxT(qs * 16 + rl, ks * 4 + gk)]);
                s = __builtin_amdgcn_mfma_f32_16x16x32_bf16(kf, qf, s, 0, 0, 0);
            }
            sfr[2 * t + T] = s;
        }
    }
    // ---- stats: lane's q = qs*16+rl; sum exp over own 128 k, reduce gk, cross-wave
    float ssum = 0.f;
#pragma unroll
    for (int i = 0; i < 32; ++i)
#pragma unroll
        for (int j = 0; j < 4; ++j) ssum += __expf(sfr[i][j] * 0.125f);
    ssum += __shfl_xor(ssum, 16);
    ssum += __shfl_xor(ssum, 32);
    if (lane < 16) pS[w][lane] = ssum;
    LWAIT; BARRIER;                                  // all K readers done; buf0/1 free
    gld8_v128x64(Vtz,      1024, LKV[0], w, lane);   // V chunks 0,1 overlap stats
    gld8_v128x64(Vtz + 64, 1024, LKV[1], w, lane);
    if (tid < 64)
        rowInv[tid] = 1.0f / (pS[tid >> 4][tid & 15] + pS[4 + (tid >> 4)][tid & 15]);
    LWAIT; BARRIER;
    const float Iq = rowInv[qs * 16 + rl];           // lane's q-row normalizer
    // V-read slot-permutation constants (absorb A's k order into B reads)
    const int g1 = kh * 4 + (gk >> 1), o1 = (gk & 1) << 2;
    // ---- pass 2: PV partials over own kh-half + direct attn stores
    f32x4 po[8] = {};                                // O_partial[q=qs*16+gk*4+j][e=n*16+rl]
#pragma unroll
    for (int t = 0; t < 16; ++t) {
        if (t == 0)       { VWAIT(2); }
        else if (t == 1)  { VWAIT(4); }
        else if (t == 15) { VWAIT(4); }
        else              { VWAIT(6); }              // V(t) landed; V(t+1)+2 stores fly
        BARRIER;
        if (t < 14)
            gld8_v128x64(Vtz + (t + 2) * 64, 1024, LKV[(t + 2) % 3], w, lane);
        float pe0[4], pe1[4];
#pragma unroll
        for (int j = 0; j < 4; ++j) {
            pe0[j] = __expf(sfr[2 * t][j] * 0.125f);
            pe1[j] = __expf(sfr[2 * t + 1][j] * 0.125f);
        }
        union { u32 w4[4]; bf16x8 v; } pa;
        pa.w4[0] = cvtpk(pe0[0], pe0[1]);
        pa.w4[1] = cvtpk(pe0[2], pe0[3]);
        pa.w4[2] = cvtpk(pe1[0], pe1[1]);
        pa.w4[3] = cvtpk(pe1[2], pe1[3]);
        // direct normalized attn stores: lane q-row, 4 consecutive k, twice
        *reinterpret_cast<float4*>(
            &attnZ[(int64_t)(qs * 16 + rl) * 1024 + t * 64 + kh * 32 + gk * 4])
            = make_float4(pe0[0] * Iq, pe0[1] * Iq, pe0[2] * Iq, pe0[3] * Iq);
        *reinterpret_cast<float4*>(
            &attnZ[(int64_t)(qs * 16 + rl) * 1024 + t * 64 + kh * 32 + 16 + gk * 4])
            = make_float4(pe1[0] * Iq, pe1[1] * Iq, pe1[2] * Iq, pe1[3] * Iq);
        const u16* LVc = LKV[t % 3];
#pragma unroll
        for (int n = 0; n < 8; ++n) {
            const int row = n * 16 + rl;
            s16x4 lo = *reinterpret_cast<const s16x4*>(
                &LVc[row * 64 + ((g1 ^ (row & 7)) << 3) + o1]);
            s16x4 hi = *reinterpret_cast<const s16x4*>(
                &LVc[row * 64 + (((g1 + 2) ^ (row & 7)) << 3) + o1]);
            bf16x8 bv = __builtin_shufflevector(lo, hi, 0, 1, 2, 3, 4, 5, 6, 7);
            po[n] = __builtin_amdgcn_mfma_f32_16x16x32_bf16(pa.v, bv, po[n], 0, 0, 0);
        }
    }
    // ---- epilogue: cross-kh reduce (LDS) + normalize + scatter to Obf
    BARRIER;                                         // all pass-2 LDS reads done
    float* POb = reinterpret_cast<float*>(&LKV[0][0]);   // [64 q][132] f32 (33.8KB)
    if (kh == 0) {
#pragma unroll
        for (int n = 0; n < 8; ++n)
#pragma unroll
            for (int j = 0; j < 4; ++j)
                POb[(qs * 16 + gk * 4 + j) * 132 + n * 16 + rl] = po[n][j];
    }
    LWAIT; BARRIER;
    if (kh == 1) {
        const int poh = h >> 3, cb2 = (h & 7) << 7;
#pragma unroll
        for (int j = 0; j < 4; ++j) {
            const int ql = qs * 16 + gk * 4 + j;
            const float IqO = rowInv[ql];
            const int qrow = m0 + ql;
#pragma unroll
            for (int n = 0; n < 8; ++n) {
                const float v = (po[n][j] + POb[ql * 132 + n * 16 + rl]) * IqO;
                Obf[((int64_t)b * 2048 + 2 * qrow + poh) * 1024
                    + cb2 + n * 16 + rl] = f2bf(v);
            }
        }
    }
}

// ---------------- K4: out = o @ w_proj^T + b_proj  (hi-only bf16)  [R8 proven form]
__global__ __launch_bounds__(256, 2) void k4_out(const u16* __restrict__ Obf,
                                                 const u16* __restrict__ Phw,
                                                 const float* __restrict__ bias,
                                                 float* __restrict__ out) {
    __shared__ u16 LA[4096], LB[4096];
    const int tid = threadIdx.x, lane = tid & 63, w = tid >> 6;
    const int wrow = (w >> 1) << 6, wcol = (w & 1) << 6;
    const int n0 = blockIdx.x << 7, m0 = blockIdx.y << 7;
    const u16* Ab = Obf + (int64_t)m0 * 1024;
    const u16* Bb = Phw + (int64_t)n0 * 1024;
    f32x4 acc[4][4] = {};
    for (int kb = 0; kb < 32; ++kb) {
        gld_p128x32(Ab + kb * 32, 1024, LA, w, lane);
        gld_p128x32(Bb + kb * 32, 1024, LB, w, lane);
        __syncthreads();
        mfma_step1(LA, LB, wrow, wcol, lane, acc);
        __syncthreads();
    }
    const int r4 = (lane >> 4) << 2, cc = lane & 15;
#pragma unroll
    for (int m = 0; m < 4; ++m)
#pragma unroll
        for (int n = 0; n < 4; ++n)
#pragma unroll
            for (int j = 0; j < 4; ++j)
                out[(int64_t)(m0 + wrow + m * 16 + r4 + j) * 1024
                    + (n0 + wcol + n * 16 + cc)]
                    = acc[m][n][j] + bias[n0 + wcol + n * 16 + cc];
}

extern "C" void kernel_launch(void* const* d_in, const int* in_sizes, int n_in,
                              void* d_out, int out_size, void* d_ws, size_t ws_size,
                              hipStream_t stream) {
    const float* x     = (const float*)d_in[0];
    const float* ctx   = (const float*)d_in[1];
    const float* wqkv  = (const float*)d_in[2];
    const float* wproj = (const float*)d_in[3];
    const float* bias  = (const float*)d_in[4];
    float* out  = (float*)d_out;                 // [4,2048,1024]
    float* attn = out + 8388608;                 // [4,16,1024,1024] f32

    // ws (u16), total 92.3 MB
    u16* Qh  = (u16*)d_ws;                       // [8192,3072]
    u16* Vt  = Qh + 25165824;                    // [64,128,1024]
    u16* Wh  = Vt + 8388608;                     // [3072,1024]
    u16* Phw = Wh + 3145728;                     // [1024,1024]
    u16* Obf = Phw + 1048576;                    // [8192,1024]

    // X bf16 plane parked in the attn region (dead once k1 finishes)
    u16* Xh = (u16*)attn;                        // [8192,1024]

    k0_all   <<<dim3(6144),   256, 0, stream>>>(wqkv, x, ctx, wproj, Wh, Xh, Phw);
    k1_qkv   <<<dim3(24, 64), 256, 0, stream>>>(Xh, Wh, Qh);
    k0v_vt   <<<dim3(8, 64),  256, 0, stream>>>(Qh, Vt);
    k23_fused<<<dim3(1024),   512, 0, stream>>>(Qh, Vt, attn, Obf);
    k4_out   <<<dim3(8, 64),  256, 0, stream>>>(Obf, Phw, bias, out);
}

// Round 13
// 244.537 us; speedup vs baseline: 1.0877x; 1.0384x over previous
//
#include <hip/hip_runtime.h>
#include <stdint.h>

typedef short bf16x8 __attribute__((ext_vector_type(8)));
typedef short s16x4 __attribute__((ext_vector_type(4)));
typedef unsigned short us8 __attribute__((ext_vector_type(8)));
typedef float f32x4 __attribute__((ext_vector_type(4)));
typedef unsigned short u16;
typedef unsigned int u32;

__device__ __forceinline__ u16 f2bf(float f) {
    u32 u = __float_as_uint(f);
    return (u16)((u + 0x7FFFu + ((u >> 16) & 1u)) >> 16);   // RNE
}
__device__ __forceinline__ float bf2f(u16 h) { return __uint_as_float(((u32)h) << 16); }

__device__ __forceinline__ u32 cvtpk(float lo, float hi) {   // D.lo=bf16(lo), D.hi=bf16(hi)
    u32 r;
    asm("v_cvt_pk_bf16_f32 %0, %1, %2" : "=v"(r) : "v"(lo), "v"(hi));
    return r;
}

typedef __attribute__((address_space(3))) unsigned int lds_uint;
typedef const __attribute__((address_space(1))) unsigned int glb_uint;
__device__ __forceinline__ void gld16(const void* g, void* l) {
    __builtin_amdgcn_global_load_lds((glb_uint*)g, (lds_uint*)l, 16, 0, 0);
}

#define VWAIT(n) asm volatile("s_waitcnt vmcnt(" #n ") lgkmcnt(0)" ::: "memory")
#define LWAIT    asm volatile("s_waitcnt lgkmcnt(0)" ::: "memory")
#define BARRIER  do { __builtin_amdgcn_s_barrier(); __builtin_amdgcn_sched_barrier(0); } while (0)

// ---- swizzled staging (rule #21: linear LDS dest + pre-swizzled per-lane global
//      source + matching XOR on the ds_read side) ----

// [128 rows][32 cols] bf16 tile (4-wave); slot = g ^ ((row>>1)&3)
__device__ __forceinline__ void gld_p128x32(const u16* __restrict__ g, int64_t stride,
                                            u16* lds, int w, int lane) {
#pragma unroll
    for (int i = 0; i < 2; ++i) {
        const int grp = w * 2 + i;
        const int row = grp * 16 + (lane >> 2);
        const int sl = (lane & 3) ^ ((row >> 1) & 3);
        gld16(g + (int64_t)row * stride + (sl << 3), &lds[grp * 512]);
    }
}
__device__ __forceinline__ int idx128x32(int row, int gk) {
    return row * 32 + ((gk ^ ((row >> 1) & 3)) << 3);
}

// [R rows][128 cols] bf16 tile (4-wave, R=32 or 64); slot = g ^ (row&7)
__device__ __forceinline__ void gld_t32x128(const u16* __restrict__ g, int64_t stride,
                                            u16* lds, int w, int lane) {
#pragma unroll
    for (int i = 0; i < 2; ++i) {
        const int gg = w * 2 + i;
        const int row = gg * 4 + (lane >> 4);
        const int gs = (lane & 15) ^ (row & 7);
        gld16(g + (int64_t)row * stride + (gs << 3), &lds[gg * 512]);
    }
}
__device__ __forceinline__ void gld_t64x128(const u16* __restrict__ g, int64_t stride,
                                            u16* lds, int w, int lane) {
#pragma unroll
    for (int i = 0; i < 4; ++i) {
        const int gg = w * 4 + i;
        const int row = gg * 4 + (lane >> 4);
        const int gs = (lane & 15) ^ (row & 7);
        gld16(g + (int64_t)row * stride + (gs << 3), &lds[gg * 512]);
    }
}
__device__ __forceinline__ int idxT(int row, int gk) {    // [*][128] read
    return row * 128 + ((gk ^ (row & 7)) << 3);
}

// [128 rows][64 cols] bf16 tile (V^T chunk, 4-wave); slot = g3 ^ (row&7)
__device__ __forceinline__ void gld_v128x64(const u16* __restrict__ g, int64_t stride,
                                            u16* lds, int w, int lane) {
#pragma unroll
    for (int i = 0; i < 4; ++i) {
        const int seg = w * 4 + i;
        const int row = seg * 8 + (lane >> 3);
        const int gs = (lane & 7) ^ (row & 7);
        gld16(g + (int64_t)row * stride + (gs << 3), &lds[seg * 512]);
    }
}
__device__ __forceinline__ int idxV(int row, int g3) {    // [128][64] read
    return row * 64 + ((g3 ^ (row & 7)) << 3);
}

// hi-only MFMA step on two swizzled [128][32] planes (4 waves, 64x64 per wave)
__device__ __forceinline__ void mfma_step1(const u16* LA, const u16* LB,
                                           int wrow, int wcol, int lane,
                                           f32x4 acc[4][4]) {
    const int rl = lane & 15, gk = lane >> 4;
    bf16x8 a[4], bv[4];
#pragma unroll
    for (int i = 0; i < 4; ++i) {
        a[i]  = *reinterpret_cast<const bf16x8*>(&LA[idx128x32(wrow + i * 16 + rl, gk)]);
        bv[i] = *reinterpret_cast<const bf16x8*>(&LB[idx128x32(wcol + i * 16 + rl, gk)]);
    }
#pragma unroll
    for (int m = 0; m < 4; ++m)
#pragma unroll
        for (int n = 0; n < 4; ++n)
            acc[m][n] = __builtin_amdgcn_mfma_f32_16x16x32_bf16(a[m], bv[n], acc[m][n], 0, 0, 0);
}

// ---------------- K0: all four f32->bf16 conversions in one launch
__global__ void k0_all(const float* __restrict__ wqkv, const float* __restrict__ x,
                       const float* __restrict__ ctx, const float* __restrict__ wproj,
                       u16* __restrict__ Wh, u16* __restrict__ Xh,
                       u16* __restrict__ Phw) {
    const int gid = blockIdx.x;
    const float* src; u16* dst; int mode; int lg;
    if (gid < 1536)      { src = wqkv;  dst = Wh;  mode = 0; lg = gid; }
    else if (gid < 3584) { src = x;     dst = Xh;  mode = 1; lg = gid - 1536; }
    else if (gid < 5632) { src = ctx;   dst = Xh;  mode = 2; lg = gid - 3584; }
    else                 { src = wproj; dst = Phw; mode = 0; lg = gid - 5632; }
    const int64_t base = ((int64_t)lg * 256 + threadIdx.x) * 8;
    const int row = (int)(base >> 10), col = (int)(base & 1023);
    int orow = row;
    if (mode == 1) orow = row + ((row >> 10) << 10);
    else if (mode == 2) orow = row + (((row >> 10) + 1) << 10);
    const float4* sp = reinterpret_cast<const float4*>(src + base);
    float4 a = sp[0], b = sp[1];
    float v[8] = {a.x, a.y, a.z, a.w, b.x, b.y, b.z, b.w};
    us8 hh;
#pragma unroll
    for (int j = 0; j < 8; ++j) hh[j] = f2bf(v[j]);
    *reinterpret_cast<us8*>(&dst[(int64_t)orow * 1024 + col]) = hh;
}

// ---------------- K1: qkv = xc @ w_qkv^T  (hi-only bf16) -> Qh  [R8 proven form]
__global__ __launch_bounds__(256, 2) void k1_qkv(const u16* __restrict__ Xh,
                                                 const u16* __restrict__ Wh,
                                                 u16* __restrict__ Qh) {
    __shared__ u16 LA[4096], LB[4096];
    const int tid = threadIdx.x, lane = tid & 63, w = tid >> 6;
    const int wrow = (w >> 1) << 6, wcol = (w & 1) << 6;
    const int n0 = blockIdx.x << 7, m0 = blockIdx.y << 7;
    const u16* Ab = Xh + (int64_t)m0 * 1024;
    const u16* Bb = Wh + (int64_t)n0 * 1024;
    f32x4 acc[4][4] = {};
    for (int kb = 0; kb < 32; ++kb) {
        gld_p128x32(Ab + kb * 32, 1024, LA, w, lane);
        gld_p128x32(Bb + kb * 32, 1024, LB, w, lane);
        __syncthreads();
        mfma_step1(LA, LB, wrow, wcol, lane, acc);
        __syncthreads();
    }
    const int r4 = (lane >> 4) << 2, cc = lane & 15;
#pragma unroll
    for (int m = 0; m < 4; ++m)
#pragma unroll
        for (int n = 0; n < 4; ++n)
#pragma unroll
            for (int j = 0; j < 4; ++j)
                Qh[(int64_t)(m0 + wrow + m * 16 + r4 + j) * 3072
                   + (n0 + wcol + n * 16 + cc)] = f2bf(acc[m][n][j]);
}

// ---------------- K0v: pre-transpose V planes: Vt[z][e 128][kpos 1024]
__global__ __launch_bounds__(256, 2) void k0v_vt(const u16* __restrict__ Qh,
                                                 u16* __restrict__ Vt) {
    __shared__ u16 T[128][144];
    const int tid = threadIdx.x;
    const int z = blockIdx.y, b = z >> 4, h = z & 15;
    const int kt = blockIdx.x;                       // 128-kpos tile
    const int c0v = (h < 8) ? (1024 + h * 128) : (2048 + (h - 8) * 128);
    const u16* Vbase = Qh + ((int64_t)b * 2048 + 1) * 3072 + c0v;
    const int row = tid >> 1, e0 = (tid & 1) << 6;
    const u16* src = Vbase + (int64_t)(kt * 128 + row) * 6144 + e0;
#pragma unroll
    for (int i = 0; i < 8; ++i) {
        us8 v = *reinterpret_cast<const us8*>(src + i * 8);
#pragma unroll
        for (int j = 0; j < 8; ++j) T[e0 + i * 8 + j][row] = v[j];
    }
    __syncthreads();
    const int e = tid >> 1, k0 = (tid & 1) << 6;
    u16* dst = Vt + ((int64_t)z << 17) + (int64_t)e * 1024 + kt * 128 + k0;
#pragma unroll
    for (int i = 0; i < 8; ++i)
        *reinterpret_cast<us8*>(dst + i * 8) = *reinterpret_cast<const us8*>(&T[e][k0 + i * 8]);
}

// ---------------- K23 v5: v3 structure + EXP-ONCE. Pass 1 computes p~=exp(s/8)
// under the K-load shadow, packs to bf16 pairs (cvt_pk) -> pk regs (64 VGPR,
// was 128 f32). Pass 2 has NO exp and NO f2bf: Ph write = packed words; attn
// store = shift-unpack * Iq. Sum stays f32-exact; attn gains <=2^-9 rel error.
__global__ __launch_bounds__(256, 2) void k23_fused(const u16* __restrict__ Qh,
                                                    const u16* __restrict__ Vt,
                                                    float* __restrict__ attn,
                                                    u16* __restrict__ Obf) {
    __shared__ u16 LQ[4096];                         // 32x128
    __shared__ u16 LKV[3][8192];                     // 3 x (64x128 K | 128x64 V^T)
    __shared__ u16 Ph[32 * 72];                      // p~ bf16 [q][k] (+pad)
    __shared__ float pS[4][32];
    __shared__ float rowInv[32];
    const int tid = threadIdx.x, lane = tid & 63, w = tid >> 6;
    const u32 wgid = blockIdx.x;
    const int xcd = wgid & 7, t0 = wgid >> 3;        // T1: same-z -> same XCD
    const int mt = t0 & 31, z = ((t0 >> 5) << 3) + xcd;
    const int b = z >> 4, h = z & 15;
    const int m0 = mt << 5;                          // 32 q-rows per block
    const u16* Qbase = Qh + ((int64_t)b * 2048 + 2 * m0) * 3072 + h * 128;
    const int pk  = (h < 8) ? 0 : 1;
    const int c0k = (h < 8) ? (2048 + h * 128) : ((h - 8) * 128);
    const u16* Kbase = Qh + ((int64_t)b * 2048 + pk) * 3072 + c0k;
    const u16* Vtz = Vt + ((int64_t)z << 17);
    float* attnZ = attn + ((int64_t)z << 20) + (int64_t)m0 * 1024;
    const int rl = lane & 15, gk = lane >> 4;
    const int r4 = gk << 2;
    const int sm = w & 1, sn = w >> 1;               // PV roles: q-half, e-half
    gld_t32x128(Qbase, 6144, LQ, w, lane);
    gld_t64x128(Kbase,             6144, LKV[0], w, lane);
    gld_t64x128(Kbase + 64 * 6144, 6144, LKV[1], w, lane);
    // ---- pass 1: swapped mfma(K,Q) -> s, EXP-ONCE -> packed p~ + running sums
    // pk0/pk1[2t+T]: q = T*16+rl, k = t*64 + w*16 + {r4..r4+3} (lo pair / hi pair)
    u32 pk0[32], pk1[32];
    float ssum0 = 0.f, ssum1 = 0.f;
#pragma unroll
    for (int t = 0; t < 16; ++t) {
        if (t == 15) { VWAIT(0); } else { VWAIT(4); }   // K(t) landed; K(t+1) in flight
        BARRIER;
        if (t < 14)
            gld_t64x128(Kbase + (int64_t)(t + 2) * 64 * 6144, 6144, LKV[(t + 2) % 3], w, lane);
        f32x4 s0 = {}, s1 = {};
#pragma unroll
        for (int ks = 0; ks < 4; ++ks) {
            bf16x8 kf = *reinterpret_cast<const bf16x8*>(&LKV[t % 3][idxT(w * 16 + rl, ks * 4 + gk)]);
            bf16x8 q0 = *reinterpret_cast<const bf16x8*>(&LQ[idxT(rl, ks * 4 + gk)]);
            bf16x8 q1 = *reinterpret_cast<const bf16x8*>(&LQ[idxT(16 + rl, ks * 4 + gk)]);
            s0 = __builtin_amdgcn_mfma_f32_16x16x32_bf16(kf, q0, s0, 0, 0, 0);
            s1 = __builtin_amdgcn_mfma_f32_16x16x32_bf16(kf, q1, s1, 0, 0, 0);
        }
        float p0[4], p1[4];
#pragma unroll
        for (int j = 0; j < 4; ++j) {
            p0[j] = __expf(s0[j] * 0.125f); ssum0 += p0[j];
            p1[j] = __expf(s1[j] * 0.125f); ssum1 += p1[j];
        }
        pk0[2 * t]     = cvtpk(p0[0], p0[1]);
        pk1[2 * t]     = cvtpk(p0[2], p0[3]);
        pk0[2 * t + 1] = cvtpk(p1[0], p1[1]);
        pk1[2 * t + 1] = cvtpk(p1[2], p1[3]);
    }
    // ---- stats: reduce sums over k (gk groups), cross-wave combine
    ssum0 += __shfl_xor(ssum0, 16); ssum0 += __shfl_xor(ssum0, 32);
    ssum1 += __shfl_xor(ssum1, 16); ssum1 += __shfl_xor(ssum1, 32);
    if (lane < 16) { pS[w][lane] = ssum0; pS[w][16 + lane] = ssum1; }
    LWAIT; BARRIER;                                  // all K readers done; buf0/1 free
    gld_v128x64(Vtz,      1024, LKV[0], w, lane);    // V chunks 0,1 overlap stats
    gld_v128x64(Vtz + 64, 1024, LKV[1], w, lane);
    if (tid < 32)
        rowInv[tid] = 1.0f / (pS[0][tid] + pS[1][tid] + pS[2][tid] + pS[3][tid]);
    LWAIT; BARRIER;
    const float Iq0 = rowInv[rl], Iq1 = rowInv[16 + rl];
    float IqO[4];
#pragma unroll
    for (int j = 0; j < 4; ++j) IqO[j] = rowInv[sm * 16 + r4 + j];
    // ---- pass 2: Ph <- packed words; attn <- shift-unpack * Iq; PV MFMA
    f32x4 po[4] = {};
#pragma unroll
    for (int t = 0; t < 16; ++t) {
        if (t == 0)       { VWAIT(4); }
        else if (t == 15) { VWAIT(2); }
        else              { VWAIT(6); }              // V(t) landed; V(t+1)+2 stores fly
        BARRIER;
        if (t < 14)
            gld_v128x64(Vtz + (t + 2) * 64, 1024, LKV[(t + 2) % 3], w, lane);
        const u32 a0 = pk0[2 * t], a1 = pk1[2 * t];
        const u32 b0 = pk0[2 * t + 1], b1 = pk1[2 * t + 1];
        *reinterpret_cast<uint2*>(&Ph[rl * 72 + w * 16 + r4])        = make_uint2(a0, a1);
        *reinterpret_cast<uint2*>(&Ph[(16 + rl) * 72 + w * 16 + r4]) = make_uint2(b0, b1);
        *reinterpret_cast<float4*>(&attnZ[(int64_t)rl * 1024 + t * 64 + w * 16 + r4])
            = make_float4(__uint_as_float(a0 << 16) * Iq0,
                          __uint_as_float(a0 & 0xFFFF0000u) * Iq0,
                          __uint_as_float(a1 << 16) * Iq0,
                          __uint_as_float(a1 & 0xFFFF0000u) * Iq0);
        *reinterpret_cast<float4*>(&attnZ[(int64_t)(16 + rl) * 1024 + t * 64 + w * 16 + r4])
            = make_float4(__uint_as_float(b0 << 16) * Iq1,
                          __uint_as_float(b0 & 0xFFFF0000u) * Iq1,
                          __uint_as_float(b1 << 16) * Iq1,
                          __uint_as_float(b1 & 0xFFFF0000u) * Iq1);
        LWAIT; BARRIER;                              // Ph visible (stores NOT drained)
        bf16x8 pa0 = *reinterpret_cast<const bf16x8*>(&Ph[(sm * 16 + rl) * 72 + gk * 8]);
        bf16x8 pa1 = *reinterpret_cast<const bf16x8*>(&Ph[(sm * 16 + rl) * 72 + 32 + gk * 8]);
#pragma unroll
        for (int n = 0; n < 4; ++n) {
            bf16x8 bv0 = *reinterpret_cast<const bf16x8*>(&LKV[t % 3][idxV(sn * 64 + n * 16 + rl, gk)]);
            bf16x8 bv1 = *reinterpret_cast<const bf16x8*>(&LKV[t % 3][idxV(sn * 64 + n * 16 + rl, 4 + gk)]);
            po[n] = __builtin_amdgcn_mfma_f32_16x16x32_bf16(pa0, bv0, po[n], 0, 0, 0);
            po[n] = __builtin_amdgcn_mfma_f32_16x16x32_bf16(pa1, bv1, po[n], 0, 0, 0);
        }
    }
    const int poh = h >> 3, cb2 = (h & 7) << 7;
#pragma unroll
    for (int n = 0; n < 4; ++n)
#pragma unroll
        for (int j = 0; j < 4; ++j) {
            const int qrow = m0 + sm * 16 + r4 + j;
            Obf[((int64_t)b * 2048 + 2 * qrow + poh) * 1024
                + cb2 + sn * 64 + n * 16 + rl] = f2bf(po[n][j] * IqO[j]);
        }
}

// ---------------- K4: out = o @ w_proj^T + b_proj  (hi-only bf16)  [R8 proven form]
__global__ __launch_bounds__(256, 2) void k4_out(const u16* __restrict__ Obf,
                                                 const u16* __restrict__ Phw,
                                                 const float* __restrict__ bias,
                                                 float* __restrict__ out) {
    __shared__ u16 LA[4096], LB[4096];
    const int tid = threadIdx.x, lane = tid & 63, w = tid >> 6;
    const int wrow = (w >> 1) << 6, wcol = (w & 1) << 6;
    const int n0 = blockIdx.x << 7, m0 = blockIdx.y << 7;
    const u16* Ab = Obf + (int64_t)m0 * 1024;
    const u16* Bb = Phw + (int64_t)n0 * 1024;
    f32x4 acc[4][4] = {};
    for (int kb = 0; kb < 32; ++kb) {
        gld_p128x32(Ab + kb * 32, 1024, LA, w, lane);
        gld_p128x32(Bb + kb * 32, 1024, LB, w, lane);
        __syncthreads();
        mfma_step1(LA, LB, wrow, wcol, lane, acc);
        __syncthreads();
    }
    const int r4 = (lane >> 4) << 2, cc = lane & 15;
#pragma unroll
    for (int m = 0; m < 4; ++m)
#pragma unroll
        for (int n = 0; n < 4; ++n)
#pragma unroll
            for (int j = 0; j < 4; ++j)
                out[(int64_t)(m0 + wrow + m * 16 + r4 + j) * 1024
                    + (n0 + wcol + n * 16 + cc)]
                    = acc[m][n][j] + bias[n0 + wcol + n * 16 + cc];
}

extern "C" void kernel_launch(void* const* d_in, const int* in_sizes, int n_in,
                              void* d_out, int out_size, void* d_ws, size_t ws_size,
                              hipStream_t stream) {
    const float* x     = (const float*)d_in[0];
    const float* ctx   = (const float*)d_in[1];
    const float* wqkv  = (const float*)d_in[2];
    const float* wproj = (const float*)d_in[3];
    const float* bias  = (const float*)d_in[4];
    float* out  = (float*)d_out;                 // [4,2048,1024]
    float* attn = out + 8388608;                 // [4,16,1024,1024] f32

    // ws (u16), total 92.3 MB
    u16* Qh  = (u16*)d_ws;                       // [8192,3072]
    u16* Vt  = Qh + 25165824;                    // [64,128,1024]
    u16* Wh  = Vt + 8388608;                     // [3072,1024]
    u16* Phw = Wh + 3145728;                     // [1024,1024]
    u16* Obf = Phw + 1048576;                    // [8192,1024]

    // X bf16 plane parked in the attn region (dead once k1 finishes)
    u16* Xh = (u16*)attn;                        // [8192,1024]

    k0_all   <<<dim3(6144),   256, 0, stream>>>(wqkv, x, ctx, wproj, Wh, Xh, Phw);
    k1_qkv   <<<dim3(24, 64), 256, 0, stream>>>(Xh, Wh, Qh);
    k0v_vt   <<<dim3(8, 64),  256, 0, stream>>>(Qh, Vt);
    k23_fused<<<dim3(2048),   256, 0, stream>>>(Qh, Vt, attn, Obf);
    k4_out   <<<dim3(8, 64),  256, 0, stream>>>(Obf, Phw, bias, out);
}